// Round 10
// baseline (128.185 us; speedup 1.0000x reference)
//
#include <hip/hip_runtime.h>

typedef unsigned char u8;
typedef unsigned short u16;
typedef float f32x4 __attribute__((ext_vector_type(4)));
typedef int i32x4 __attribute__((ext_vector_type(4)));
typedef int i32x8 __attribute__((ext_vector_type(8)));

#define NROWS 16384
#define DIM 128

// exp(-2*sim) = exp2(sim * -2*log2(e)); scale folded into normalized B rows.
#define NEG2LOG2E -2.8853900817779268f
#define SCALE ((float)(1.0 / (16384.0 * 16383.0)))

// E8M0 scale byte 127 = 2^0 = 1.0, replicated.
#define SCALE1 0x7F7F7F7F

#define KMAX 320

// Two rows per wave (half-wave per row): float4 loads, half-wave shuffle
// reduction, paired cvt_pk_fp8 -> one dword store per lane (fully coalesced).
// B rows pre-scaled by -2*log2(e) so GEMM output feeds exp2 directly.
__global__ __launch_bounds__(256) void norm_kernel(
    const float* __restrict__ a, const float* __restrict__ b,
    u8* __restrict__ aO, u8* __restrict__ bO)
{
    int tid  = threadIdx.x;
    int lane = tid & 63;
    int w    = tid >> 6;
    int half = lane >> 5;
    int l32  = lane & 31;
    long row = (long)blockIdx.x * 8 + w * 2 + half;

    const float4 va = ((const float4*)(a + row * DIM))[l32];
    float sa = va.x * va.x + va.y * va.y + va.z * va.z + va.w * va.w;
    #pragma unroll
    for (int off = 16; off; off >>= 1) sa += __shfl_xor(sa, off, 64);
    float inva = 1.0f / fmaxf(sqrtf(sa), 1e-12f);
    int pa = __builtin_amdgcn_cvt_pk_fp8_f32(va.x * inva, va.y * inva, 0, false);
    pa = __builtin_amdgcn_cvt_pk_fp8_f32(va.z * inva, va.w * inva, pa, true);
    ((int*)(aO + row * DIM))[l32] = pa;

    const float4 vb = ((const float4*)(b + row * DIM))[l32];
    float sb = vb.x * vb.x + vb.y * vb.y + vb.z * vb.z + vb.w * vb.w;
    #pragma unroll
    for (int off = 16; off; off >>= 1) sb += __shfl_xor(sb, off, 64);
    float invb = NEG2LOG2E / fmaxf(sqrtf(sb), 1e-12f);
    int pb = __builtin_amdgcn_cvt_pk_fp8_f32(vb.x * invb, vb.y * invb, 0, false);
    pb = __builtin_amdgcn_cvt_pk_fp8_f32(vb.z * invb, vb.w * invb, pb, true);
    ((int*)(bO + row * DIM))[l32] = pb;
}

// Grid (33,128). x<32: maskless 128x512 GEMM strip (sums exp over ALL pairs).
// x==32, y<100: correction block for label y — self-scan labels, gather that
// label's rows from global (L2-hot), redo the SAME MX-MFMA + exp2 on the
// same-label pairs, emit per-label sum for exact subtraction in reduce.
// Corr blocks are co-resident with gemm blocks, so their gather latency is
// hidden (standalone corr dispatch measured 39 us of pure latency in R8).
__global__ __launch_bounds__(256, 3) void gemm_kernel(
    const u8* __restrict__ A, const u8* __restrict__ B,
    const int* __restrict__ labels,
    float* __restrict__ partials, float* __restrict__ corrP)
{
    __shared__ u8 sA[16384];
    __shared__ u8 sB[2][16384];

    int tid  = threadIdx.x;
    int lane = tid & 63;
    int w    = tid >> 6;
    int mrow = lane & 15;
    int q    = lane >> 4;

    if (blockIdx.x == 32) {
        // ---------------- correction path ----------------
        if (blockIdx.y >= 100) return;
        int l = blockIdx.y;
        int* sIdx = (int*)sA;                 // KMAX ints
        __shared__ int sCnt;
        __shared__ float red[4];
        if (tid == 0) sCnt = 0;
        __syncthreads();

        for (int i = tid; i < NROWS; i += 256)
            if (labels[i] == l) {
                int p = atomicAdd(&sCnt, 1);
                if (p < KMAX) sIdx[p] = i;
            }
        __syncthreads();

        int k = sCnt < KMAX ? sCnt : KMAX;
        int nt = (k + 15) >> 4;
        int ntk = nt << 4;
        for (int r = k + tid; r < ntk; r += 256) sIdx[r] = sIdx[0];  // pad
        __syncthreads();

        float s = 0.0f;
        for (int tp = w; tp < nt * nt; tp += 4) {
            int ti = tp / nt, tj = tp - ti * nt;
            int ri = sIdx[ti * 16 + mrow];
            int rj = sIdx[tj * 16 + mrow];
            const u8* pa = A + (size_t)ri * DIM + q * 32;
            const u8* pb = B + (size_t)rj * DIM + q * 32;
            i32x8 aF, bF;
            *((i32x4*)&aF)     = *(const i32x4*)pa;
            *((i32x4*)&aF + 1) = *(const i32x4*)(pa + 16);
            *((i32x4*)&bF)     = *(const i32x4*)pb;
            *((i32x4*)&bF + 1) = *(const i32x4*)(pb + 16);
            f32x4 acc = (f32x4){0.f, 0.f, 0.f, 0.f};
            acc = __builtin_amdgcn_mfma_scale_f32_16x16x128_f8f6f4(
                aF, bF, acc, 0, 0, 0, SCALE1, 0, SCALE1);
            int i0 = ti * 16 + q * 4;
            int j  = tj * 16 + mrow;
            #pragma unroll
            for (int r = 0; r < 4; r++) {
                float e = __builtin_amdgcn_exp2f(acc[r]);
                s += ((i0 + r) < k && j < k) ? e : 0.0f;
            }
        }

        #pragma unroll
        for (int off = 32; off; off >>= 1) s += __shfl_xor(s, off, 64);
        if (lane == 0) red[w] = s;
        __syncthreads();
        if (tid == 0)
            corrP[l] = (red[0] + red[1] + red[2] + red[3]) * SCALE;
        return;
    }

    // ---------------- maskless GEMM path ----------------
    int wr = w >> 1;
    int wc = w & 1;

    int rowBase = blockIdx.y * 128;
    int colBase = blockIdx.x * 512;

    // Staging pattern: LDS granule g of row m holds global granule g^(m&7).
    int m0 = tid >> 3;
    int p0 = tid & 7;
    int srcOff = m0 * 128 + ((p0 ^ (m0 & 7)) << 4);
    int ldsOff = (tid - lane) * 16;      // wave-uniform base

    const u8* gA = A + (size_t)rowBase * DIM + srcOff;
    const u8* gB = B + (size_t)colBase * DIM + srcOff;

    {
        const u8* gpA = gA;
        const u8* gpB = gB;
        u8* lpA = &sA[ldsOff];
        u8* lpB = &sB[0][ldsOff];
        #pragma unroll
        for (int it = 0; it < 4; it++) {
            __builtin_amdgcn_global_load_lds(
                (const __attribute__((address_space(1))) void*)gpA,
                (__attribute__((address_space(3))) void*)lpA, 16, 0, 0);
            __builtin_amdgcn_global_load_lds(
                (const __attribute__((address_space(1))) void*)gpB,
                (__attribute__((address_space(3))) void*)lpB, 16, 0, 0);
            gpA += 4096; gpB += 4096; lpA += 4096; lpB += 4096;
        }
    }

    // Fragment LDS byte offsets: low granule (2q)^(row&7); high = ^16.
    int aOff[4], bOff[4];
    #pragma unroll
    for (int mi = 0; mi < 4; mi++) {
        int m = wr * 64 + mi * 16 + mrow;
        aOff[mi] = m * 128 + (((q << 1) ^ (m & 7)) << 4);
        int n = wc * 64 + mi * 16 + mrow;
        bOff[mi] = n * 128 + (((q << 1) ^ (n & 7)) << 4);
    }

    __syncthreads();   // A + B0 resident

    // A operands register-resident for all 4 tiles (32 VGPRs).
    i32x8 a8[4];
    #pragma unroll
    for (int mi = 0; mi < 4; mi++) {
        *((i32x4*)&a8[mi])     = *(const i32x4*)(sA + aOff[mi]);
        *((i32x4*)&a8[mi] + 1) = *(const i32x4*)(sA + (aOff[mi] ^ 16));
    }

    float s = 0.0f;

    #pragma unroll
    for (int jt = 0; jt < 4; jt++) {
        if (jt < 3) {
            const u8* gp = gB + (jt + 1) * (128 * DIM);
            u8* lp = &sB[(jt + 1) & 1][ldsOff];
            #pragma unroll
            for (int it = 0; it < 4; it++) {
                __builtin_amdgcn_global_load_lds(
                    (const __attribute__((address_space(1))) void*)gp,
                    (__attribute__((address_space(3))) void*)lp, 16, 0, 0);
                gp += 4096; lp += 4096;
            }
        }

        const u8* sb = sB[jt & 1];
        i32x8 b8[4];
        #pragma unroll
        for (int ni = 0; ni < 4; ni++) {
            *((i32x4*)&b8[ni])     = *(const i32x4*)(sb + bOff[ni]);
            *((i32x4*)&b8[ni] + 1) = *(const i32x4*)(sb + (bOff[ni] ^ 16));
        }

        f32x4 acc[4][4];
        #pragma unroll
        for (int mi = 0; mi < 4; mi++)
            #pragma unroll
            for (int ni = 0; ni < 4; ni++)
                acc[mi][ni] = (f32x4){0.f, 0.f, 0.f, 0.f};

        #pragma unroll
        for (int mi = 0; mi < 4; mi++)
            #pragma unroll
            for (int ni = 0; ni < 4; ni++)
                acc[mi][ni] = __builtin_amdgcn_mfma_scale_f32_16x16x128_f8f6f4(
                    a8[mi], b8[ni], acc[mi][ni], 0, 0, 0, SCALE1, 0, SCALE1);

        // Maskless epilogue: exp2 + add only.
        float s0 = 0.0f, s1 = 0.0f;
        #pragma unroll
        for (int mi = 0; mi < 4; mi++)
            #pragma unroll
            for (int ni = 0; ni < 4; ni++)
                #pragma unroll
                for (int r = 0; r < 4; r++) {
                    float e = __builtin_amdgcn_exp2f(acc[mi][ni][r]);
                    if (r & 1) s1 += e; else s0 += e;
                }
        s += s0 + s1;

        __syncthreads();
    }

    #pragma unroll
    for (int off = 32; off; off >>= 1) s += __shfl_xor(s, off, 64);

    float* red = (float*)sA;
    if (lane == 0) red[w] = s;
    __syncthreads();
    if (tid == 0) {
        float t = (red[0] + red[1]) + (red[2] + red[3]);
        partials[blockIdx.y * 32 + blockIdx.x] = t * SCALE;
    }
}

__global__ __launch_bounds__(256) void reduce_kernel(
    const float* __restrict__ gP, const float* __restrict__ cP,
    float* __restrict__ out)
{
    int tid = threadIdx.x;
    const float4* p4 = (const float4*)gP;
    float s = 0.0f;
    #pragma unroll 4
    for (int i = tid; i < 1024; i += 256) {
        float4 v = p4[i];
        s += (v.x + v.y) + (v.z + v.w);
    }
    if (tid < 100) s -= cP[tid];
    #pragma unroll
    for (int off = 32; off; off >>= 1) s += __shfl_xor(s, off, 64);
    __shared__ float red[4];
    if ((tid & 63) == 0) red[tid >> 6] = s;
    __syncthreads();
    if (tid == 0) out[0] = (red[0] + red[1]) + (red[2] + red[3]);
}

extern "C" void kernel_launch(void* const* d_in, const int* in_sizes, int n_in,
                              void* d_out, int out_size, void* d_ws, size_t ws_size,
                              hipStream_t stream) {
    const float* self_p = (const float*)d_in[0];
    const float* pos_p  = (const float*)d_in[1];
    const int*   labels = (const int*)d_in[2];
    float* out = (float*)d_out;

    u8* aB = (u8*)d_ws;                         // 2 MB fp8 normalized self
    u8* bB = aB + (size_t)NROWS * DIM;          // 2 MB fp8 normalized pos (pre-scaled)
    float* gemmP = (float*)(bB + (size_t)NROWS * DIM);     // 16 KB
    float* corrP = gemmP + 4096;                            // 512 B (100 used)

    norm_kernel<<<NROWS / 8, 256, 0, stream>>>(self_p, pos_p, aB, bB);
    gemm_kernel<<<dim3(33, 128), 256, 0, stream>>>(aB, bB, labels, gemmP, corrP);
    reduce_kernel<<<1, 256, 0, stream>>>(gemmP, corrP, out);
}

// Round 11
// 112.741 us; speedup vs baseline: 1.1370x; 1.1370x over previous
//
#include <hip/hip_runtime.h>

typedef unsigned char u8;
typedef unsigned short u16;
typedef float f32x4 __attribute__((ext_vector_type(4)));
typedef int i32x4 __attribute__((ext_vector_type(4)));
typedef int i32x8 __attribute__((ext_vector_type(8)));

#define NROWS 16384
#define DIM 128

// exp(-2*sim) = exp2(sim * -2*log2(e)); scale folded into normalized B rows.
#define NEG2LOG2E -2.8853900817779268f
#define SCALE ((float)(1.0 / (16384.0 * 16383.0)))

// E8M0 scale byte 127 = 2^0 = 1.0, replicated.
#define SCALE1 0x7F7F7F7F

#define KMAX 320
#define NCORR 100
#define NGEMM 4096

// Two rows per wave (half-wave per row): float4 loads, half-wave shuffle
// reduction, paired cvt_pk_fp8 -> one dword store per lane (fully coalesced).
// B rows pre-scaled by -2*log2(e) so GEMM output feeds exp2 directly.
__global__ __launch_bounds__(256) void norm_kernel(
    const float* __restrict__ a, const float* __restrict__ b,
    u8* __restrict__ aO, u8* __restrict__ bO)
{
    int tid  = threadIdx.x;
    int lane = tid & 63;
    int w    = tid >> 6;
    int half = lane >> 5;
    int l32  = lane & 31;
    long row = (long)blockIdx.x * 8 + w * 2 + half;

    const float4 va = ((const float4*)(a + row * DIM))[l32];
    float sa = va.x * va.x + va.y * va.y + va.z * va.z + va.w * va.w;
    #pragma unroll
    for (int off = 16; off; off >>= 1) sa += __shfl_xor(sa, off, 64);
    float inva = 1.0f / fmaxf(sqrtf(sa), 1e-12f);
    int pa = __builtin_amdgcn_cvt_pk_fp8_f32(va.x * inva, va.y * inva, 0, false);
    pa = __builtin_amdgcn_cvt_pk_fp8_f32(va.z * inva, va.w * inva, pa, true);
    ((int*)(aO + row * DIM))[l32] = pa;

    const float4 vb = ((const float4*)(b + row * DIM))[l32];
    float sb = vb.x * vb.x + vb.y * vb.y + vb.z * vb.z + vb.w * vb.w;
    #pragma unroll
    for (int off = 16; off; off >>= 1) sb += __shfl_xor(sb, off, 64);
    float invb = NEG2LOG2E / fmaxf(sqrtf(sb), 1e-12f);
    int pb = __builtin_amdgcn_cvt_pk_fp8_f32(vb.x * invb, vb.y * invb, 0, false);
    pb = __builtin_amdgcn_cvt_pk_fp8_f32(vb.z * invb, vb.w * invb, pb, true);
    ((int*)(bO + row * DIM))[l32] = pb;
}

// 1D grid of 100 + 4096 blocks. IDs 0..99: correction block for label id —
// dispatched FIRST so their latency chains hide under the gemm fill phase
// and their L2 pollution is confined to warm-up (R10's spread placement cost
// +23 us tail and +7 GB HBM churn). IDs 100+: maskless 128x512 GEMM strip
// (sums exp over ALL pairs); same-label sums subtracted exactly in reduce.
__global__ __launch_bounds__(256, 3) void gemm_kernel(
    const u8* __restrict__ A, const u8* __restrict__ B,
    const int* __restrict__ labels,
    float* __restrict__ partials, float* __restrict__ corrP)
{
    __shared__ u8 sA[16384];
    __shared__ u8 sB[2][16384];

    int tid  = threadIdx.x;
    int lane = tid & 63;
    int w    = tid >> 6;
    int mrow = lane & 15;
    int q    = lane >> 4;

    if (blockIdx.x < NCORR) {
        // ---------------- correction path (early blocks) ----------------
        int l = blockIdx.x;
        int* sIdx = (int*)sA;                 // KMAX ints
        __shared__ int sCnt;
        __shared__ float red[4];
        if (tid == 0) sCnt = 0;
        __syncthreads();

        for (int i = tid; i < NROWS; i += 256)
            if (labels[i] == l) {
                int p = atomicAdd(&sCnt, 1);
                if (p < KMAX) sIdx[p] = i;
            }
        __syncthreads();

        int k = sCnt < KMAX ? sCnt : KMAX;
        int nt = (k + 15) >> 4;
        int ntk = nt << 4;
        for (int r = k + tid; r < ntk; r += 256) sIdx[r] = sIdx[0];  // pad
        __syncthreads();

        int npairs = nt * nt;
        float s = 0.0f;
        // 2-deep software pipeline: two tile-pairs per iteration, gathers
        // issued together so their L2 latency overlaps.
        for (int tp = w; tp < npairs; tp += 8) {
            int tpB = tp + 4;
            bool has2 = tpB < npairs;
            int tp2 = has2 ? tpB : tp;

            int ti1 = tp / nt,  tj1 = tp  - ti1 * nt;
            int ti2 = tp2 / nt, tj2 = tp2 - ti2 * nt;
            int ri1 = sIdx[ti1 * 16 + mrow], rj1 = sIdx[tj1 * 16 + mrow];
            int ri2 = sIdx[ti2 * 16 + mrow], rj2 = sIdx[tj2 * 16 + mrow];

            const u8* pa1 = A + (size_t)ri1 * DIM + q * 32;
            const u8* pb1 = B + (size_t)rj1 * DIM + q * 32;
            const u8* pa2 = A + (size_t)ri2 * DIM + q * 32;
            const u8* pb2 = B + (size_t)rj2 * DIM + q * 32;

            i32x8 aF1, bF1, aF2, bF2;
            *((i32x4*)&aF1)     = *(const i32x4*)pa1;
            *((i32x4*)&aF1 + 1) = *(const i32x4*)(pa1 + 16);
            *((i32x4*)&bF1)     = *(const i32x4*)pb1;
            *((i32x4*)&bF1 + 1) = *(const i32x4*)(pb1 + 16);
            *((i32x4*)&aF2)     = *(const i32x4*)pa2;
            *((i32x4*)&aF2 + 1) = *(const i32x4*)(pa2 + 16);
            *((i32x4*)&bF2)     = *(const i32x4*)pb2;
            *((i32x4*)&bF2 + 1) = *(const i32x4*)(pb2 + 16);

            f32x4 acc1 = (f32x4){0.f, 0.f, 0.f, 0.f};
            f32x4 acc2 = (f32x4){0.f, 0.f, 0.f, 0.f};
            acc1 = __builtin_amdgcn_mfma_scale_f32_16x16x128_f8f6f4(
                aF1, bF1, acc1, 0, 0, 0, SCALE1, 0, SCALE1);
            acc2 = __builtin_amdgcn_mfma_scale_f32_16x16x128_f8f6f4(
                aF2, bF2, acc2, 0, 0, 0, SCALE1, 0, SCALE1);

            int i1 = ti1 * 16 + q * 4, j1 = tj1 * 16 + mrow;
            int i2 = ti2 * 16 + q * 4, j2 = tj2 * 16 + mrow;
            #pragma unroll
            for (int r = 0; r < 4; r++) {
                float e1 = __builtin_amdgcn_exp2f(acc1[r]);
                s += ((i1 + r) < k && j1 < k) ? e1 : 0.0f;
                float e2 = __builtin_amdgcn_exp2f(acc2[r]);
                s += (has2 && (i2 + r) < k && j2 < k) ? e2 : 0.0f;
            }
        }

        #pragma unroll
        for (int off = 32; off; off >>= 1) s += __shfl_xor(s, off, 64);
        if (lane == 0) red[w] = s;
        __syncthreads();
        if (tid == 0)
            corrP[l] = (red[0] + red[1] + red[2] + red[3]) * SCALE;
        return;
    }

    // ---------------- maskless GEMM path ----------------
    int g  = blockIdx.x - NCORR;
    int wr = w >> 1;
    int wc = w & 1;

    int rowBase = (g >> 5) * 128;
    int colBase = (g & 31) * 512;

    // Staging pattern: LDS granule g of row m holds global granule g^(m&7).
    int m0 = tid >> 3;
    int p0 = tid & 7;
    int srcOff = m0 * 128 + ((p0 ^ (m0 & 7)) << 4);
    int ldsOff = (tid - lane) * 16;      // wave-uniform base

    const u8* gA = A + (size_t)rowBase * DIM + srcOff;
    const u8* gB = B + (size_t)colBase * DIM + srcOff;

    {
        const u8* gpA = gA;
        const u8* gpB = gB;
        u8* lpA = &sA[ldsOff];
        u8* lpB = &sB[0][ldsOff];
        #pragma unroll
        for (int it = 0; it < 4; it++) {
            __builtin_amdgcn_global_load_lds(
                (const __attribute__((address_space(1))) void*)gpA,
                (__attribute__((address_space(3))) void*)lpA, 16, 0, 0);
            __builtin_amdgcn_global_load_lds(
                (const __attribute__((address_space(1))) void*)gpB,
                (__attribute__((address_space(3))) void*)lpB, 16, 0, 0);
            gpA += 4096; gpB += 4096; lpA += 4096; lpB += 4096;
        }
    }

    // Fragment LDS byte offsets: low granule (2q)^(row&7); high = ^16.
    int aOff[4], bOff[4];
    #pragma unroll
    for (int mi = 0; mi < 4; mi++) {
        int m = wr * 64 + mi * 16 + mrow;
        aOff[mi] = m * 128 + (((q << 1) ^ (m & 7)) << 4);
        int n = wc * 64 + mi * 16 + mrow;
        bOff[mi] = n * 128 + (((q << 1) ^ (n & 7)) << 4);
    }

    __syncthreads();   // A + B0 resident

    // A operands register-resident for all 4 tiles (32 VGPRs).
    i32x8 a8[4];
    #pragma unroll
    for (int mi = 0; mi < 4; mi++) {
        *((i32x4*)&a8[mi])     = *(const i32x4*)(sA + aOff[mi]);
        *((i32x4*)&a8[mi] + 1) = *(const i32x4*)(sA + (aOff[mi] ^ 16));
    }

    float s = 0.0f;

    #pragma unroll
    for (int jt = 0; jt < 4; jt++) {
        if (jt < 3) {
            const u8* gp = gB + (jt + 1) * (128 * DIM);
            u8* lp = &sB[(jt + 1) & 1][ldsOff];
            #pragma unroll
            for (int it = 0; it < 4; it++) {
                __builtin_amdgcn_global_load_lds(
                    (const __attribute__((address_space(1))) void*)gp,
                    (__attribute__((address_space(3))) void*)lp, 16, 0, 0);
                gp += 4096; lp += 4096;
            }
        }

        const u8* sb = sB[jt & 1];
        i32x8 b8[4];
        #pragma unroll
        for (int ni = 0; ni < 4; ni++) {
            *((i32x4*)&b8[ni])     = *(const i32x4*)(sb + bOff[ni]);
            *((i32x4*)&b8[ni] + 1) = *(const i32x4*)(sb + (bOff[ni] ^ 16));
        }

        f32x4 acc[4][4];
        #pragma unroll
        for (int mi = 0; mi < 4; mi++)
            #pragma unroll
            for (int ni = 0; ni < 4; ni++)
                acc[mi][ni] = (f32x4){0.f, 0.f, 0.f, 0.f};

        #pragma unroll
        for (int mi = 0; mi < 4; mi++)
            #pragma unroll
            for (int ni = 0; ni < 4; ni++)
                acc[mi][ni] = __builtin_amdgcn_mfma_scale_f32_16x16x128_f8f6f4(
                    a8[mi], b8[ni], acc[mi][ni], 0, 0, 0, SCALE1, 0, SCALE1);

        // Maskless epilogue: exp2 + add only.
        float s0 = 0.0f, s1 = 0.0f;
        #pragma unroll
        for (int mi = 0; mi < 4; mi++)
            #pragma unroll
            for (int ni = 0; ni < 4; ni++)
                #pragma unroll
                for (int r = 0; r < 4; r++) {
                    float e = __builtin_amdgcn_exp2f(acc[mi][ni][r]);
                    if (r & 1) s1 += e; else s0 += e;
                }
        s += s0 + s1;

        __syncthreads();
    }

    #pragma unroll
    for (int off = 32; off; off >>= 1) s += __shfl_xor(s, off, 64);

    float* red = (float*)sA;
    if (lane == 0) red[w] = s;
    __syncthreads();
    if (tid == 0) {
        float t = (red[0] + red[1]) + (red[2] + red[3]);
        partials[g] = t * SCALE;
    }
}

__global__ __launch_bounds__(256) void reduce_kernel(
    const float* __restrict__ gP, const float* __restrict__ cP,
    float* __restrict__ out)
{
    int tid = threadIdx.x;
    const float4* p4 = (const float4*)gP;
    float s = 0.0f;
    #pragma unroll 4
    for (int i = tid; i < 1024; i += 256) {
        float4 v = p4[i];
        s += (v.x + v.y) + (v.z + v.w);
    }
    if (tid < NCORR) s -= cP[tid];
    #pragma unroll
    for (int off = 32; off; off >>= 1) s += __shfl_xor(s, off, 64);
    __shared__ float red[4];
    if ((tid & 63) == 0) red[tid >> 6] = s;
    __syncthreads();
    if (tid == 0) out[0] = (red[0] + red[1]) + (red[2] + red[3]);
}

extern "C" void kernel_launch(void* const* d_in, const int* in_sizes, int n_in,
                              void* d_out, int out_size, void* d_ws, size_t ws_size,
                              hipStream_t stream) {
    const float* self_p = (const float*)d_in[0];
    const float* pos_p  = (const float*)d_in[1];
    const int*   labels = (const int*)d_in[2];
    float* out = (float*)d_out;

    u8* aB = (u8*)d_ws;                         // 2 MB fp8 normalized self
    u8* bB = aB + (size_t)NROWS * DIM;          // 2 MB fp8 normalized pos (pre-scaled)
    float* gemmP = (float*)(bB + (size_t)NROWS * DIM);     // 16 KB
    float* corrP = gemmP + NGEMM;                           // 400 B (100 used)

    norm_kernel<<<NROWS / 8, 256, 0, stream>>>(self_p, pos_p, aB, bB);
    gemm_kernel<<<NCORR + NGEMM, 256, 0, stream>>>(aB, bB, labels, gemmP, corrP);
    reduce_kernel<<<1, 256, 0, stream>>>(gemmP, corrP, out);
}